// Round 2
// baseline (185.826 us; speedup 1.0000x reference)
//
#include <hip/hip_runtime.h>

#define RELS 237
#define DIM 128
#define EPS 1e-12f

// ws layout (int32):
//   [0,   256)  : per-relation counts
//   [256, 512)  : per-relation exclusive offsets
//   [512, 768)  : per-relation atomic cursors
//   [768, 768+N): triple indices grouped (sorted) by relation

__global__ void k_zero(int* __restrict__ ws) {
    int t = threadIdx.x;
    if (t < RELS) ws[t] = 0;
}

__global__ void k_count(const int* __restrict__ r_typ, int* __restrict__ ws, int n) {
    int i = blockIdx.x * blockDim.x + threadIdx.x;
    if (i < n) atomicAdd(&ws[r_typ[i]], 1);
}

__global__ void k_scan(int* __restrict__ ws) {
    if (threadIdx.x == 0) {
        int acc = 0;
        for (int r = 0; r < RELS; ++r) {
            ws[256 + r] = acc;   // offsets
            ws[512 + r] = acc;   // cursors
            acc += ws[r];
        }
    }
}

__global__ void k_scatter(const int* __restrict__ r_typ, int* __restrict__ ws, int n) {
    int i = blockIdx.x * blockDim.x + threadIdx.x;
    if (i < n) {
        int pos = atomicAdd(&ws[512 + r_typ[i]], 1);
        ws[768 + pos] = i;
    }
}

// One workgroup per relation. R (128x128 fp32 = 64KB) staged in LDS with an
// XOR column swizzle (row k, logical float4-col c stored at c ^ (k&31)):
// keeps LDS at exactly 64KB and spreads ds_read_b128 across banks optimally
// (8 touches/bank = the b128 bandwidth floor).
__global__ __launch_bounds__(256, 1) void relgemm(
    const float* __restrict__ ent,
    const int*   __restrict__ h_ids,
    const int*   __restrict__ t_ids,
    const int*   __restrict__ sorted,
    const int*   __restrict__ offs,
    const int*   __restrict__ cnts,
    float*       __restrict__ out)
{
    __shared__ float4 Rs4[DIM * 32];  // 64 KB

    const int tid  = threadIdx.x;
    const int lane = tid & 63;
    const int tgrp = tid >> 6;        // wave id 0..3
    const int r    = blockIdx.x;

    // ---- stage R: relation block = ent rows [r*128, r*128+128) (contiguous 64KB)
    const float4* Rg = (const float4*)ent + ((long)r << 12);
    #pragma unroll
    for (int j = 0; j < 16; ++j) {
        int g = j * 256 + tid;        // 0..4095 float4s
        int k = g >> 5;
        int c = g & 31;
        Rs4[(k << 5) | (c ^ (k & 31))] = Rg[g];
    }
    const int base = offs[r];
    const int cnt  = cnts[r];
    __syncthreads();

    const int sw = lane & 31;                         // same swizzle for k=lane and k=lane+64
    const float4* rowA = Rs4 + (lane << 5);           // row k  = lane
    const float4* rowB = Rs4 + ((lane + 64) << 5);    // row k' = lane+64

    for (int p = 0; p < cnt; p += 24) {
        int npass = cnt - p; if (npass > 24) npass = 24;

        // this wave owns triples t = tgrp*6 + tt (dummies clamp to last valid)
        int idxv[6];
        const float4* hp[6];
        #pragma unroll
        for (int tt = 0; tt < 6; ++tt) {
            int t  = tgrp * 6 + tt;
            int ts = t < npass ? t : npass - 1;
            int idx = __builtin_amdgcn_readfirstlane(sorted[base + p + ts]);
            idxv[tt] = idx;
            int hid = __builtin_amdgcn_readfirstlane(h_ids[idx]);
            hp[tt] = (const float4*)ent + ((long)hid << 5);
        }

        float acc0[6], acc1[6];
        #pragma unroll
        for (int tt = 0; tt < 6; ++tt) { acc0[tt] = 0.f; acc1[tt] = 0.f; }

        #pragma unroll 4
        for (int d4 = 0; d4 < 32; ++d4) {
            float4 ra = rowA[d4 ^ sw];
            float4 rb = rowB[d4 ^ sw];
            #pragma unroll
            for (int tt = 0; tt < 6; ++tt) {
                float4 hv = hp[tt][d4];   // wave-uniform address (L1/scalar-friendly)
                acc0[tt] += hv.x * ra.x + hv.y * ra.y + hv.z * ra.z + hv.w * ra.w;
                acc1[tt] += hv.x * rb.x + hv.y * rb.y + hv.z * rb.z + hv.w * rb.w;
            }
        }

        // epilogue: out = sqrt(2 - 2*<p,t>/(|p||t|))  (h-normalization folds out)
        #pragma unroll
        for (int tt = 0; tt < 6; ++tt) {
            int t   = tgrp * 6 + tt;
            int idx = idxv[tt];
            int trow = __builtin_amdgcn_readfirstlane(t_ids[idx]);
            const float* tv = ent + ((long)trow << 7);
            float tv0 = tv[lane], tv1 = tv[lane + 64];
            float p0 = acc0[tt], p1 = acc1[tt];
            float sp  = p0 * p0 + p1 * p1;     // |prod|^2 partial
            float st  = tv0 * tv0 + tv1 * tv1; // |t|^2 partial
            float spt = p0 * tv0 + p1 * tv1;   // <prod,t> partial
            #pragma unroll
            for (int m = 32; m >= 1; m >>= 1) {
                sp  += __shfl_xor(sp,  m, 64);
                st  += __shfl_xor(st,  m, 64);
                spt += __shfl_xor(spt, m, 64);
            }
            if (lane == 0 && t < npass) {
                float npn = fmaxf(sqrtf(sp), EPS);
                float ntn = fmaxf(sqrtf(st), EPS);
                float cth = spt / (npn * ntn);
                float v   = 2.0f - 2.0f * cth;
                out[idx] = sqrtf(fmaxf(v, 0.0f));
            }
        }
    }
}

extern "C" void kernel_launch(void* const* d_in, const int* in_sizes, int n_in,
                              void* d_out, int out_size, void* d_ws, size_t ws_size,
                              hipStream_t stream) {
    const float* ent   = (const float*)d_in[0];
    const int*   h_ids = (const int*)d_in[1];
    const int*   r_typ = (const int*)d_in[2];
    const int*   t_ids = (const int*)d_in[3];
    float* out = (float*)d_out;
    int*   ws  = (int*)d_ws;
    const int n = in_sizes[1];
    const int nb = (n + 255) / 256;

    hipLaunchKernelGGL(k_zero,    dim3(1),    dim3(256), 0, stream, ws);
    hipLaunchKernelGGL(k_count,   dim3(nb),   dim3(256), 0, stream, r_typ, ws, n);
    hipLaunchKernelGGL(k_scan,    dim3(1),    dim3(64),  0, stream, ws);
    hipLaunchKernelGGL(k_scatter, dim3(nb),   dim3(256), 0, stream, r_typ, ws, n);
    hipLaunchKernelGGL(relgemm,   dim3(RELS), dim3(256), 0, stream,
                       ent, h_ids, t_ids, ws + 768, ws + 256, ws, out);
}

// Round 3
// 143.435 us; speedup vs baseline: 1.2955x; 1.2955x over previous
//
#include <hip/hip_runtime.h>

#define RELS 237
#define DIM 128
#define CH 24          // triples per chunk (= one pass per workgroup)
#define MAXCHUNK 912   // sum ceil(c_r/24) <= (16384 + 237*23)/24 = 909
#define EPS 1e-12f

// ws layout (int32):
//   [0,   256)   : per-relation counts            (zeroed by memsetAsync)
//   [256, 512)   : per-relation exclusive offsets
//   [512, 768)   : per-relation atomic cursors
//   [768]        : n_chunks
//   [800, 1712)  : chunk worklist, entry = (r<<16)|j  (chunk j of relation r)
//   [2048, 2048+N): triple indices grouped by relation

__global__ void k_count(const int* __restrict__ r_typ, int* __restrict__ ws, int n) {
    int i = blockIdx.x * blockDim.x + threadIdx.x;
    if (i < n) atomicAdd(&ws[r_typ[i]], 1);
}

// One block, 256 threads: exclusive scan of counts -> offs/cursors, then
// scan of per-relation chunk counts -> chunk worklist + n_chunks.
__global__ void k_scan(int* __restrict__ ws) {
    __shared__ int s[256];
    const int t = threadIdx.x;
    const int c = (t < RELS) ? ws[t] : 0;
    s[t] = c; __syncthreads();
    #pragma unroll
    for (int off = 1; off < 256; off <<= 1) {
        int v = (t >= off) ? s[t - off] : 0;
        __syncthreads();
        s[t] += v; __syncthreads();
    }
    const int excl = s[t] - c;
    if (t < RELS) { ws[256 + t] = excl; ws[512 + t] = excl; }

    // chunk-count scan
    const int nch = (c + CH - 1) / CH;
    __syncthreads();
    s[t] = nch; __syncthreads();
    #pragma unroll
    for (int off = 1; off < 256; off <<= 1) {
        int v = (t >= off) ? s[t - off] : 0;
        __syncthreads();
        s[t] += v; __syncthreads();
    }
    const int choff = s[t] - nch;
    if (t == 255) ws[768] = s[255];
    for (int j = 0; j < nch; ++j) ws[800 + choff + j] = (t << 16) | j;
}

__global__ void k_scatter(const int* __restrict__ r_typ, int* __restrict__ ws, int n) {
    int i = blockIdx.x * blockDim.x + threadIdx.x;
    if (i < n) {
        int pos = atomicAdd(&ws[512 + r_typ[i]], 1);
        ws[2048 + pos] = i;
    }
}

// One workgroup per chunk (relation r, triples [j*CH, j*CH+len)).
// R (128x128 fp32 = 64KB) staged in LDS with XOR column swizzle; the chunk's
// h-vectors (<=24 x 512B = 12KB) staged in LDS with coalesced loads so the
// inner loop is pure LDS (no long-latency global gathers in the hot loop).
__global__ __launch_bounds__(256, 2) void relgemm(
    const float* __restrict__ ent,
    const int*   __restrict__ h_ids,
    const int*   __restrict__ t_ids,
    const int*   __restrict__ ws,
    float*       __restrict__ out)
{
    __shared__ float4 Rs4[DIM * 32];    // 64 KB
    __shared__ float4 Hs4[CH * 32];     // 12 KB
    __shared__ int    sidx[CH];

    const int cid = blockIdx.x;
    if (cid >= ws[768]) return;

    const int tid  = threadIdx.x;
    const int lane = tid & 63;
    const int tgrp = tid >> 6;

    const int entry = ws[800 + cid];
    const int r     = entry >> 16;
    const int j     = entry & 0xffff;
    const int cnt   = ws[r];
    const int start = j * CH;
    const int base  = ws[256 + r] + start;
    int len = cnt - start; if (len > CH) len = CH;

    const int* sorted = ws + 2048;

    // ---- stage R: rows [r*128, r*128+128), contiguous 64KB, XOR swizzle
    const float4* Rg = (const float4*)ent + ((long)r << 12);
    #pragma unroll
    for (int s = 0; s < 16; ++s) {
        int g = s * 256 + tid;          // 0..4095 float4s
        int k = g >> 5;
        int c = g & 31;
        Rs4[(k << 5) | (c ^ (k & 31))] = Rg[g];
    }

    // ---- stage h rows: thread handles 3 float4s; triple t = g>>5, col c = g&31
    #pragma unroll
    for (int s = 0; s < 3; ++s) {
        int g  = s * 256 + tid;         // 0..767
        int t  = g >> 5;
        int c  = g & 31;
        int tc = t < len ? t : len - 1;
        int idx = sorted[base + tc];
        if (c == 0) sidx[t] = idx;
        int hid = h_ids[idx];
        Hs4[(t << 5) | c] = ((const float4*)ent)[((long)hid << 5) + c];
    }
    __syncthreads();

    const int sw = lane & 31;
    const float4* rowA = Rs4 + (lane << 5);          // k  = lane
    const float4* rowB = Rs4 + ((lane + 64) << 5);   // k' = lane+64

    // this wave owns triples t = tgrp*6 + tt (dummies clamp to last valid)
    float acc0[6], acc1[6];
    #pragma unroll
    for (int tt = 0; tt < 6; ++tt) { acc0[tt] = 0.f; acc1[tt] = 0.f; }

    int tloc[6];
    #pragma unroll
    for (int tt = 0; tt < 6; ++tt) {
        int t = tgrp * 6 + tt;
        tloc[tt] = t < len ? t : len - 1;
    }

    #pragma unroll 4
    for (int d4 = 0; d4 < 32; ++d4) {
        float4 ra = rowA[d4 ^ sw];
        float4 rb = rowB[d4 ^ sw];
        #pragma unroll
        for (int tt = 0; tt < 6; ++tt) {
            float4 hv = Hs4[(tloc[tt] << 5) | d4];   // broadcast, conflict-free
            acc0[tt] += hv.x * ra.x + hv.y * ra.y + hv.z * ra.z + hv.w * ra.w;
            acc1[tt] += hv.x * rb.x + hv.y * rb.y + hv.z * rb.z + hv.w * rb.w;
        }
    }

    // epilogue: out = sqrt(2 - 2*<p,t>/(|p||t|))  (h-normalization folds out)
    #pragma unroll
    for (int tt = 0; tt < 6; ++tt) {
        int t   = tgrp * 6 + tt;
        int idx = sidx[tloc[tt]];
        int trow = __builtin_amdgcn_readfirstlane(t_ids[idx]);
        const float* tv = ent + ((long)trow << 7);
        float tv0 = tv[lane], tv1 = tv[lane + 64];
        float p0 = acc0[tt], p1 = acc1[tt];
        float sp  = p0 * p0 + p1 * p1;
        float st  = tv0 * tv0 + tv1 * tv1;
        float spt = p0 * tv0 + p1 * tv1;
        #pragma unroll
        for (int m = 32; m >= 1; m >>= 1) {
            sp  += __shfl_xor(sp,  m, 64);
            st  += __shfl_xor(st,  m, 64);
            spt += __shfl_xor(spt, m, 64);
        }
        if (lane == 0 && t < len) {
            float npn = fmaxf(sqrtf(sp), EPS);
            float ntn = fmaxf(sqrtf(st), EPS);
            float cth = spt / (npn * ntn);
            float v   = 2.0f - 2.0f * cth;
            out[idx] = sqrtf(fmaxf(v, 0.0f));
        }
    }
}

extern "C" void kernel_launch(void* const* d_in, const int* in_sizes, int n_in,
                              void* d_out, int out_size, void* d_ws, size_t ws_size,
                              hipStream_t stream) {
    const float* ent   = (const float*)d_in[0];
    const int*   h_ids = (const int*)d_in[1];
    const int*   r_typ = (const int*)d_in[2];
    const int*   t_ids = (const int*)d_in[3];
    float* out = (float*)d_out;
    int*   ws  = (int*)d_ws;
    const int n = in_sizes[1];
    const int nb = (n + 255) / 256;

    hipMemsetAsync(ws, 0, 1024, stream);   // counts (graph-capture-safe)
    hipLaunchKernelGGL(k_count,   dim3(nb),       dim3(256), 0, stream, r_typ, ws, n);
    hipLaunchKernelGGL(k_scan,    dim3(1),        dim3(256), 0, stream, ws);
    hipLaunchKernelGGL(k_scatter, dim3(nb),       dim3(256), 0, stream, r_typ, ws, n);
    hipLaunchKernelGGL(relgemm,   dim3(MAXCHUNK), dim3(256), 0, stream,
                       ent, h_ids, t_ids, ws, out);
}

// Round 4
// 134.257 us; speedup vs baseline: 1.3841x; 1.0684x over previous
//
#include <hip/hip_runtime.h>

#define RELS 237
#define DIM 128
#define CH 32           // triples per chunk
#define MAXCHUNK 742    // sum ceil(c_r/32) <= (16384 + 237*31)/32
#define EPS 1e-12f

typedef __attribute__((ext_vector_type(8))) short bf16x8;
typedef __attribute__((ext_vector_type(4))) float f32x4;

// ws layout (int32):
//   ws[1]          : n_chunks
//   ws[64..64+742) : chunk worklist, entry = (r<<20)|(base<<6)|len
//   ws[2048..+N)   : triple indices grouped by relation

__device__ __forceinline__ unsigned short f2bf(float f) {
    unsigned int u = __float_as_uint(f);
    u = (u + 0x7fffu + ((u >> 16) & 1u)) >> 16;   // RNE
    return (unsigned short)u;
}

// Single-block fused prep: histogram -> scan -> worklist -> scatter.
__global__ void k_prep(const int* __restrict__ r_typ, int* __restrict__ ws, int n) {
    __shared__ int hist[256];
    __shared__ int scn[256];
    __shared__ int curs[256];
    const int t = threadIdx.x;
    hist[t] = 0;
    __syncthreads();
    for (int i = t; i < n; i += 256) atomicAdd(&hist[r_typ[i]], 1);
    __syncthreads();
    const int c = hist[t];
    scn[t] = c; __syncthreads();
    #pragma unroll
    for (int off = 1; off < 256; off <<= 1) {
        int v = (t >= off) ? scn[t - off] : 0;
        __syncthreads();
        scn[t] += v; __syncthreads();
    }
    const int base = scn[t] - c;       // exclusive prefix
    curs[t] = base;
    const int nch = (c + CH - 1) >> 5;
    __syncthreads();
    scn[t] = nch; __syncthreads();
    #pragma unroll
    for (int off = 1; off < 256; off <<= 1) {
        int v = (t >= off) ? scn[t - off] : 0;
        __syncthreads();
        scn[t] += v; __syncthreads();
    }
    const int choff = scn[t] - nch;
    if (t == 255) ws[1] = scn[255];
    for (int j = 0; j < nch; ++j) {
        int cb  = base + j * CH;
        int len = c - j * CH; if (len > CH) len = CH;
        ws[64 + choff + j] = (t << 20) | (cb << 6) | len;
    }
    __syncthreads();
    for (int i = t; i < n; i += 256) {
        int rr  = r_typ[i];
        int pos = atomicAdd(&curs[rr], 1);
        ws[2048 + pos] = i;
    }
}

// One workgroup per 32-triple chunk of one relation. MFMA bf16 16x16x32:
// A = h (M=32 triples), B = R^T via direct row reads (B wants contiguous-K
// per lane = contiguous-d = R row order; no transpose). fp32 accumulate.
// LDS: Rb bf16[128][136] @0 (34816B), Hb bf16[32][136] @34816 (8704B),
// sidx @43520 (128B); Pp f32[32][132] @0 aliases dead Rb after mfma barrier.
__global__ __launch_bounds__(256, 3) void relgemm(
    const float* __restrict__ ent,
    const int*   __restrict__ h_ids,
    const int*   __restrict__ t_ids,
    const int*   __restrict__ ws,
    float*       __restrict__ out)
{
    __shared__ char smem[43648];
    unsigned short* Rb = (unsigned short*)smem;
    unsigned short* Hb = (unsigned short*)(smem + 34816);
    int*  sidx = (int*)(smem + 43520);
    float* Pp  = (float*)smem;

    const int cid = blockIdx.x;
    if (cid >= ws[1]) return;
    const int e    = ws[64 + cid];
    const int r    = e >> 20;
    const int base = (e >> 6) & 16383;
    const int len  = e & 63;
    const int* sorted = ws + 2048;

    const int tid  = threadIdx.x;
    const int lane = tid & 63;
    const int w    = tid >> 6;

    if (tid < CH) {
        int tc = tid < len ? tid : len - 1;
        sidx[tid] = sorted[base + tc];
    }
    __syncthreads();

    // ---- stage R (64KB fp32 -> 32KB bf16, padded stride 136)
    const float4* Rg = (const float4*)ent + ((long)r << 12);
    #pragma unroll
    for (int s = 0; s < 16; ++s) {
        int g = s * 256 + tid;
        int row = g >> 5, c4 = g & 31;
        float4 v = Rg[g];
        ushort4 b; b.x = f2bf(v.x); b.y = f2bf(v.y); b.z = f2bf(v.z); b.w = f2bf(v.w);
        *(ushort4*)(Rb + row * 136 + c4 * 4) = b;
    }
    // ---- stage h rows (32 x 512B fp32 -> bf16)
    #pragma unroll
    for (int s = 0; s < 4; ++s) {
        int g = s * 256 + tid;
        int trow = g >> 5, c4 = g & 31;
        int hid = h_ids[sidx[trow]];
        float4 v = ((const float4*)ent)[((long)hid << 5) + c4];
        ushort4 b; b.x = f2bf(v.x); b.y = f2bf(v.y); b.z = f2bf(v.z); b.w = f2bf(v.w);
        *(ushort4*)(Hb + trow * 136 + c4 * 4) = b;
    }
    __syncthreads();

    // ---- MFMA: wave w owns output cols [w*32, w*32+32)
    const int q = lane >> 4, c = lane & 15;
    const unsigned short* A0p = Hb + c * 136 + q * 8;
    const unsigned short* A1p = Hb + (c + 16) * 136 + q * 8;
    const unsigned short* B0p = Rb + (w * 32 + c) * 136 + q * 8;
    const unsigned short* B1p = Rb + (w * 32 + 16 + c) * 136 + q * 8;

    f32x4 a00 = {0.f,0.f,0.f,0.f}, a01 = a00, a10 = a00, a11 = a00;
    #pragma unroll
    for (int ks = 0; ks < 4; ++ks) {
        bf16x8 A0 = *(const bf16x8*)(A0p + ks * 32);
        bf16x8 A1 = *(const bf16x8*)(A1p + ks * 32);
        bf16x8 B0 = *(const bf16x8*)(B0p + ks * 32);
        bf16x8 B1 = *(const bf16x8*)(B1p + ks * 32);
        a00 = __builtin_amdgcn_mfma_f32_16x16x32_bf16(A0, B0, a00, 0, 0, 0);
        a01 = __builtin_amdgcn_mfma_f32_16x16x32_bf16(A0, B1, a01, 0, 0, 0);
        a10 = __builtin_amdgcn_mfma_f32_16x16x32_bf16(A1, B0, a10, 0, 0, 0);
        a11 = __builtin_amdgcn_mfma_f32_16x16x32_bf16(A1, B1, a11, 0, 0, 0);
    }
    __syncthreads();   // Rb dead; Pp aliases it

    // ---- write prod to LDS: D layout col=lane&15, row=(lane>>4)*4+reg
    #pragma unroll
    for (int reg = 0; reg < 4; ++reg) {
        int m0 = q * 4 + reg;
        Pp[m0 * 132        + w * 32      + c] = a00[reg];
        Pp[m0 * 132        + w * 32 + 16 + c] = a01[reg];
        Pp[(m0 + 16) * 132 + w * 32      + c] = a10[reg];
        Pp[(m0 + 16) * 132 + w * 32 + 16 + c] = a11[reg];
    }
    __syncthreads();

    // ---- epilogue: out = sqrt(2 - 2*<p,t>/(|p||t|)); wave w owns triples w*8..+7
    #pragma unroll
    for (int tt = 0; tt < 8; ++tt) {
        int t   = w * 8 + tt;
        int idx = sidx[t];
        int trow = __builtin_amdgcn_readfirstlane(t_ids[idx]);
        const float* tv = ent + ((long)trow << 7);
        float tv0 = tv[lane], tv1 = tv[lane + 64];
        float p0 = Pp[t * 132 + lane], p1 = Pp[t * 132 + 64 + lane];
        float sp  = p0 * p0 + p1 * p1;
        float st  = tv0 * tv0 + tv1 * tv1;
        float spt = p0 * tv0 + p1 * tv1;
        #pragma unroll
        for (int m = 32; m >= 1; m >>= 1) {
            sp  += __shfl_xor(sp,  m, 64);
            st  += __shfl_xor(st,  m, 64);
            spt += __shfl_xor(spt, m, 64);
        }
        if (lane == 0 && t < len) {
            float npn = fmaxf(sqrtf(sp), EPS);
            float ntn = fmaxf(sqrtf(st), EPS);
            float v   = 2.0f - 2.0f * (spt / (npn * ntn));
            out[idx] = sqrtf(fmaxf(v, 0.0f));
        }
    }
}

extern "C" void kernel_launch(void* const* d_in, const int* in_sizes, int n_in,
                              void* d_out, int out_size, void* d_ws, size_t ws_size,
                              hipStream_t stream) {
    const float* ent   = (const float*)d_in[0];
    const int*   h_ids = (const int*)d_in[1];
    const int*   r_typ = (const int*)d_in[2];
    const int*   t_ids = (const int*)d_in[3];
    float* out = (float*)d_out;
    int*   ws  = (int*)d_ws;
    const int n = in_sizes[1];

    hipLaunchKernelGGL(k_prep,  dim3(1),        dim3(256), 0, stream, r_typ, ws, n);
    hipLaunchKernelGGL(relgemm, dim3(MAXCHUNK), dim3(256), 0, stream,
                       ent, h_ids, t_ids, ws, out);
}

// Round 5
// 122.894 us; speedup vs baseline: 1.5121x; 1.0925x over previous
//
#include <hip/hip_runtime.h>

#define RELS 237
#define DIM 128
#define CH 32           // triples per chunk
#define MAXCHUNK 742    // sum ceil(c_r/32) <= (16384 + 237*31)/32
#define EPS 1e-12f

typedef __attribute__((ext_vector_type(8))) short bf16x8;
typedef __attribute__((ext_vector_type(4))) float f32x4;

// ws layout (int32):
//   [0,   256)   : per-relation counts (zeroed by memsetAsync)
//   [1] is NOT used for counts conflict: counts use [0,237); n_chunks at [300]
//   [320, 576)   : per-relation exclusive offsets
//   [576, 832)   : per-relation atomic cursors
//   [1024, 1024+742): chunk worklist, entry = (r<<20)|(base<<6)|len
//   [2048, 2048+N): triple indices grouped by relation

__device__ __forceinline__ unsigned short f2bf(float f) {
    unsigned int u = __float_as_uint(f);
    u = (u + 0x7fffu + ((u >> 16) & 1u)) >> 16;   // RNE
    return (unsigned short)u;
}

__global__ void k_count(const int* __restrict__ r_typ, int* __restrict__ ws, int n) {
    int i = blockIdx.x * blockDim.x + threadIdx.x;
    if (i < n) atomicAdd(&ws[r_typ[i]], 1);
}

// One tiny block: scan counts -> offs/cursors, emit chunk worklist.
__global__ void k_scanlist(int* __restrict__ ws) {
    __shared__ int scn[256];
    const int t = threadIdx.x;
    const int c = (t < RELS) ? ws[t] : 0;
    scn[t] = c; __syncthreads();
    #pragma unroll
    for (int off = 1; off < 256; off <<= 1) {
        int v = (t >= off) ? scn[t - off] : 0;
        __syncthreads();
        scn[t] += v; __syncthreads();
    }
    const int base = scn[t] - c;
    if (t < RELS) { ws[320 + t] = base; ws[576 + t] = base; }
    const int nch = (c + CH - 1) >> 5;
    __syncthreads();
    scn[t] = nch; __syncthreads();
    #pragma unroll
    for (int off = 1; off < 256; off <<= 1) {
        int v = (t >= off) ? scn[t - off] : 0;
        __syncthreads();
        scn[t] += v; __syncthreads();
    }
    const int choff = scn[t] - nch;
    if (t == 255) ws[300] = scn[255];
    for (int j = 0; j < nch; ++j) {
        int cb  = base + j * CH;
        int len = c - j * CH; if (len > CH) len = CH;
        ws[1024 + choff + j] = (t << 20) | (cb << 6) | len;
    }
}

__global__ void k_scatter(const int* __restrict__ r_typ, int* __restrict__ ws, int n) {
    int i = blockIdx.x * blockDim.x + threadIdx.x;
    if (i < n) {
        int pos = atomicAdd(&ws[576 + r_typ[i]], 1);
        ws[2048 + pos] = i;
    }
}

// One workgroup per 32-triple chunk of one relation. MFMA bf16 16x16x32:
// A = h (M=32 triples), B = R^T via direct row reads (B wants contiguous-K
// per lane = contiguous-d = R row order; no transpose). fp32 accumulate.
// LDS: Rb bf16[128][136] @0 (34816B), Hb bf16[32][136] @34816 (8704B),
// sidx @43520 (128B); Pp f32[32][132] @0 aliases dead Rb after mfma barrier.
__global__ __launch_bounds__(256, 3) void relgemm(
    const float* __restrict__ ent,
    const int*   __restrict__ h_ids,
    const int*   __restrict__ t_ids,
    const int*   __restrict__ ws,
    float*       __restrict__ out)
{
    __shared__ char smem[43648];
    unsigned short* Rb = (unsigned short*)smem;
    unsigned short* Hb = (unsigned short*)(smem + 34816);
    int*  sidx = (int*)(smem + 43520);
    float* Pp  = (float*)smem;

    const int cid = blockIdx.x;
    if (cid >= ws[300]) return;
    const int e    = ws[1024 + cid];
    const int r    = e >> 20;
    const int base = (e >> 6) & 16383;
    const int len  = e & 63;
    const int* sorted = ws + 2048;

    const int tid  = threadIdx.x;
    const int lane = tid & 63;
    const int w    = tid >> 6;

    if (tid < CH) {
        int tc = tid < len ? tid : len - 1;
        sidx[tid] = sorted[base + tc];
    }
    __syncthreads();

    // ---- stage R (64KB fp32 -> 32KB bf16, padded stride 136)
    const float4* Rg = (const float4*)ent + ((long)r << 12);
    #pragma unroll
    for (int s = 0; s < 16; ++s) {
        int g = s * 256 + tid;
        int row = g >> 5, c4 = g & 31;
        float4 v = Rg[g];
        ushort4 b; b.x = f2bf(v.x); b.y = f2bf(v.y); b.z = f2bf(v.z); b.w = f2bf(v.w);
        *(ushort4*)(Rb + row * 136 + c4 * 4) = b;
    }
    // ---- stage h rows (32 x 512B fp32 -> bf16)
    #pragma unroll
    for (int s = 0; s < 4; ++s) {
        int g = s * 256 + tid;
        int trow = g >> 5, c4 = g & 31;
        int hid = h_ids[sidx[trow]];
        float4 v = ((const float4*)ent)[((long)hid << 5) + c4];
        ushort4 b; b.x = f2bf(v.x); b.y = f2bf(v.y); b.z = f2bf(v.z); b.w = f2bf(v.w);
        *(ushort4*)(Hb + trow * 136 + c4 * 4) = b;
    }
    __syncthreads();

    // ---- MFMA: wave w owns output cols [w*32, w*32+32)
    const int q = lane >> 4, c = lane & 15;
    const unsigned short* A0p = Hb + c * 136 + q * 8;
    const unsigned short* A1p = Hb + (c + 16) * 136 + q * 8;
    const unsigned short* B0p = Rb + (w * 32 + c) * 136 + q * 8;
    const unsigned short* B1p = Rb + (w * 32 + 16 + c) * 136 + q * 8;

    f32x4 a00 = {0.f,0.f,0.f,0.f}, a01 = a00, a10 = a00, a11 = a00;
    #pragma unroll
    for (int ks = 0; ks < 4; ++ks) {
        bf16x8 A0 = *(const bf16x8*)(A0p + ks * 32);
        bf16x8 A1 = *(const bf16x8*)(A1p + ks * 32);
        bf16x8 B0 = *(const bf16x8*)(B0p + ks * 32);
        bf16x8 B1 = *(const bf16x8*)(B1p + ks * 32);
        a00 = __builtin_amdgcn_mfma_f32_16x16x32_bf16(A0, B0, a00, 0, 0, 0);
        a01 = __builtin_amdgcn_mfma_f32_16x16x32_bf16(A0, B1, a01, 0, 0, 0);
        a10 = __builtin_amdgcn_mfma_f32_16x16x32_bf16(A1, B0, a10, 0, 0, 0);
        a11 = __builtin_amdgcn_mfma_f32_16x16x32_bf16(A1, B1, a11, 0, 0, 0);
    }
    __syncthreads();   // Rb dead; Pp aliases it

    // ---- write prod to LDS: D layout col=lane&15, row=(lane>>4)*4+reg
    #pragma unroll
    for (int reg = 0; reg < 4; ++reg) {
        int m0 = q * 4 + reg;
        Pp[m0 * 132        + w * 32      + c] = a00[reg];
        Pp[m0 * 132        + w * 32 + 16 + c] = a01[reg];
        Pp[(m0 + 16) * 132 + w * 32      + c] = a10[reg];
        Pp[(m0 + 16) * 132 + w * 32 + 16 + c] = a11[reg];
    }
    __syncthreads();

    // ---- epilogue: out = sqrt(2 - 2*<p,t>/(|p||t|)); wave w owns triples w*8..+7
    #pragma unroll
    for (int tt = 0; tt < 8; ++tt) {
        int t   = w * 8 + tt;
        int idx = sidx[t];
        int trow = __builtin_amdgcn_readfirstlane(t_ids[idx]);
        const float* tv = ent + ((long)trow << 7);
        float tv0 = tv[lane], tv1 = tv[lane + 64];
        float p0 = Pp[t * 132 + lane], p1 = Pp[t * 132 + 64 + lane];
        float sp  = p0 * p0 + p1 * p1;
        float st  = tv0 * tv0 + tv1 * tv1;
        float spt = p0 * tv0 + p1 * tv1;
        #pragma unroll
        for (int m = 32; m >= 1; m >>= 1) {
            sp  += __shfl_xor(sp,  m, 64);
            st  += __shfl_xor(st,  m, 64);
            spt += __shfl_xor(spt, m, 64);
        }
        if (lane == 0 && t < len) {
            float npn = fmaxf(sqrtf(sp), EPS);
            float ntn = fmaxf(sqrtf(st), EPS);
            float v   = 2.0f - 2.0f * (spt / (npn * ntn));
            out[idx] = sqrtf(fmaxf(v, 0.0f));
        }
    }
}

extern "C" void kernel_launch(void* const* d_in, const int* in_sizes, int n_in,
                              void* d_out, int out_size, void* d_ws, size_t ws_size,
                              hipStream_t stream) {
    const float* ent   = (const float*)d_in[0];
    const int*   h_ids = (const int*)d_in[1];
    const int*   r_typ = (const int*)d_in[2];
    const int*   t_ids = (const int*)d_in[3];
    float* out = (float*)d_out;
    int*   ws  = (int*)d_ws;
    const int n = in_sizes[1];
    const int nb = (n + 255) / 256;

    hipMemsetAsync(ws, 0, 1024, stream);   // counts (graph-capture-safe)
    hipLaunchKernelGGL(k_count,    dim3(nb),       dim3(256), 0, stream, r_typ, ws, n);
    hipLaunchKernelGGL(k_scanlist, dim3(1),        dim3(256), 0, stream, ws);
    hipLaunchKernelGGL(k_scatter,  dim3(nb),       dim3(256), 0, stream, r_typ, ws, n);
    hipLaunchKernelGGL(relgemm,    dim3(MAXCHUNK), dim3(256), 0, stream,
                       ent, h_ids, t_ids, ws, out);
}